// Round 1
// baseline (1195.708 us; speedup 1.0000x reference)
//
#include <hip/hip_runtime.h>

static constexpr int   NPB  = 16384;        // rays per batch
static constexpr int   NR   = 4 * NPB;      // 65536 rays total
static constexpr int   NS   = 16;           // march steps
static constexpr int   H    = 128;          // hidden dim
static constexpr float FARV = 2.4f;
static constexpr float EPSF = 1.1920928955078125e-07f; // np.float32 eps

// ---------------------------------------------------------------------------
// Per-thread MLP eval. All weight indices are wave-uniform -> scalar loads;
// h[128] is fully register-resident (both k-loops fully unrolled).
// cv = b1 + feature @ W1[3:35]  (precomputed per batch)
// W2t[j*H + k] = W2[k*H + j]    (transposed for contiguous k-streaming)
// ---------------------------------------------------------------------------
__device__ __forceinline__ float mlp_eval(
    float px, float py, float pz,
    const float* __restrict__ W1,   // rows 0..2 used: W1[k], W1[H+k], W1[2H+k]
    const float* __restrict__ cv,   // [H]
    const float* __restrict__ W2t,  // [H][H] transposed
    const float* __restrict__ b2,   // [H]
    const float* __restrict__ W3,   // [H]
    float b3v)
{
    float h[H];
#pragma unroll
    for (int k = 0; k < H; ++k) {
        float v = cv[k];
        v = fmaf(px, W1[k], v);
        v = fmaf(py, W1[H + k], v);
        v = fmaf(pz, W1[2 * H + k], v);
        h[k] = fmaxf(v, 0.0f);
    }
    float f = b3v;
#pragma unroll 1   // keep rolled: 32 iterations, body ~512 FMA (I$ friendly)
    for (int j = 0; j < H; j += 4) {
        const float* __restrict__ w = W2t + j * H;
        float a0 = b2[j + 0], a1 = b2[j + 1], a2 = b2[j + 2], a3 = b2[j + 3];
#pragma unroll
        for (int k = 0; k < H; ++k) {
            float hk = h[k];
            a0 = fmaf(hk, w[k],         a0);
            a1 = fmaf(hk, w[H + k],     a1);
            a2 = fmaf(hk, w[2 * H + k], a2);
            a3 = fmaf(hk, w[3 * H + k], a3);
        }
        f = fmaf(fmaxf(a0, 0.0f), W3[j + 0], f);
        f = fmaf(fmaxf(a1, 0.0f), W3[j + 1], f);
        f = fmaf(fmaxf(a2, 0.0f), W3[j + 2], f);
        f = fmaf(fmaxf(a3, 0.0f), W3[j + 3], f);
    }
    return f;
}

// ---------------------------------------------------------------------------
// Prep: transpose W2 into ws, build per-batch conditioning vectors.
// ---------------------------------------------------------------------------
__global__ void k_prep(const float* __restrict__ W1, const float* __restrict__ b1,
                       const float* __restrict__ W2, const float* __restrict__ feat,
                       float* __restrict__ W2t, float* __restrict__ cva)
{
    int t = blockIdx.x * blockDim.x + threadIdx.x;   // 16384 threads
    int j = t >> 7, k = t & (H - 1);
    W2t[j * H + k] = W2[k * H + j];
    if (t < 4 * H) {
        int b = t >> 7, kk = t & (H - 1);
        float acc = b1[kk];
#pragma unroll
        for (int i = 0; i < 32; ++i)
            acc = fmaf(feat[b * 32 + i], W1[(3 + i) * H + kk], acc);
        cva[b * H + kk] = acc;
    }
}

// ---------------------------------------------------------------------------
// Phase A: one thread per (ray, step). tid = s*NR + r so f_all writes and the
// later per-step reads are coalesced.
// ---------------------------------------------------------------------------
__global__ __launch_bounds__(256, 2) void k_march(
    const float* __restrict__ ray0, const float* __restrict__ dirs,
    const float* __restrict__ W1,   const float* __restrict__ cva,
    const float* __restrict__ W2t,  const float* __restrict__ b2,
    const float* __restrict__ W3,   const float* __restrict__ b3p,
    float* __restrict__ f_all, int* __restrict__ count)
{
    int tid = blockIdx.x * blockDim.x + threadIdx.x; // 1,048,576 threads
    if (tid == 0) *count = 0;                        // zero compaction counter
    int r = tid & (NR - 1);
    int s = tid >> 16;
    float d = ((float)s * (1.0f / 15.0f)) * FARV;
    float ox = ray0[3 * r], oy = ray0[3 * r + 1], oz = ray0[3 * r + 2];
    float dx = dirs[3 * r], dy = dirs[3 * r + 1], dz = dirs[3 * r + 2];
    const float* cv = cva + (r >> 14) * H;
    float f = mlp_eval(fmaf(d, dx, ox), fmaf(d, dy, oy), fmaf(d, dz, oz),
                       W1, cv, W2t, b2, W3, *b3p);
    f_all[tid] = f;
}

// ---------------------------------------------------------------------------
// Crossing scan per ray. Unmasked rays finish here (d=FAR); masked rays are
// compacted for the refine kernel.
// ---------------------------------------------------------------------------
__global__ void k_cross(
    const float* __restrict__ ray0, const float* __restrict__ dirs,
    const float* __restrict__ f_all,
    int* __restrict__ count, int* __restrict__ ids,
    float4* __restrict__ state, float* __restrict__ out)
{
    int r = blockIdx.x * blockDim.x + threadIdx.x;   // 65536 threads
    float fv[NS];
#pragma unroll
    for (int s = 0; s < NS; ++s) fv[s] = f_all[s * NR + r];
    int idx = -1; float flo = 0.0f, fhi = 0.0f;
#pragma unroll
    for (int s = NS - 2; s >= 0; --s) {              // reverse => first crossing wins
        if (fv[s] < 0.0f && fv[s + 1] >= 0.0f) { idx = s; flo = fv[s]; fhi = fv[s + 1]; }
    }
    if (idx < 0) {
        float ox = ray0[3 * r], oy = ray0[3 * r + 1], oz = ray0[3 * r + 2];
        float dx = dirs[3 * r], dy = dirs[3 * r + 1], dz = dirs[3 * r + 2];
        out[r] = FARV;
        out[NR + 3 * r + 0] = fmaf(FARV, dx, ox);
        out[NR + 3 * r + 1] = fmaf(FARV, dy, oy);
        out[NR + 3 * r + 2] = fmaf(FARV, dz, oz);
        out[4 * NR + r] = 0.0f;
    } else {
        int slot = atomicAdd(count, 1);
        ids[slot] = r;
        float dlo = ((float)idx * (1.0f / 15.0f)) * FARV;
        float dhi = ((float)(idx + 1) * (1.0f / 15.0f)) * FARV;
        state[slot] = make_float4(dlo, flo, dhi, fhi);
    }
}

// ---------------------------------------------------------------------------
// Phase B: 8 secant iterations for compacted (masked) rays only.
// ---------------------------------------------------------------------------
__global__ __launch_bounds__(256, 2) void k_refine(
    const float* __restrict__ ray0, const float* __restrict__ dirs,
    const float* __restrict__ W1,   const float* __restrict__ cva,
    const float* __restrict__ W2t,  const float* __restrict__ b2,
    const float* __restrict__ W3,   const float* __restrict__ b3p,
    const int* __restrict__ count, const int* __restrict__ ids,
    const float4* __restrict__ state, float* __restrict__ out)
{
    int t = blockIdx.x * blockDim.x + threadIdx.x;   // 65536 threads
    if (t >= *count) return;
    int r = ids[t];
    float4 st = state[t];
    float dlo = st.x, flo = st.y, dhi = st.z, fhi = st.w;
    float ox = ray0[3 * r], oy = ray0[3 * r + 1], oz = ray0[3 * r + 2];
    float dx = dirs[3 * r], dy = dirs[3 * r + 1], dz = dirs[3 * r + 2];
    const float* cv = cva + (r >> 14) * H;
    float b3v = *b3p;
#pragma unroll 1   // do NOT unroll: 8x inlined MLP would blow the I$
    for (int it = 0; it < 8; ++it) {
        float dc  = fhi - flo;
        float den = copysignf(fmaxf(fabsf(dc), EPSF), dc);
        float dn  = dlo - (flo * (dhi - dlo)) / den;
        float fn  = mlp_eval(fmaf(dn, dx, ox), fmaf(dn, dy, oy), fmaf(dn, dz, oz),
                             W1, cv, W2t, b2, W3, b3v);
        if (fn < 0.0f) { dlo = dn; flo = fn; }
        else           { dhi = dn; fhi = fn; }
    }
    float dc  = fhi - flo;
    float den = copysignf(fmaxf(fabsf(dc), EPSF), dc);
    float dp  = dlo - (flo * (dhi - dlo)) / den;
    out[r] = dp;
    out[NR + 3 * r + 0] = fmaf(dp, dx, ox);
    out[NR + 3 * r + 1] = fmaf(dp, dy, oy);
    out[NR + 3 * r + 2] = fmaf(dp, dz, oz);
    out[4 * NR + r] = 1.0f;
}

// ---------------------------------------------------------------------------
extern "C" void kernel_launch(void* const* d_in, const int* in_sizes, int n_in,
                              void* d_out, int out_size, void* d_ws, size_t ws_size,
                              hipStream_t stream)
{
    const float* ray0 = (const float*)d_in[0];
    const float* dirs = (const float*)d_in[1];
    const float* feat = (const float*)d_in[2];
    const float* W1   = (const float*)d_in[3];
    const float* b1   = (const float*)d_in[4];
    const float* W2   = (const float*)d_in[5];
    const float* b2   = (const float*)d_in[6];
    const float* W3   = (const float*)d_in[7];
    const float* b3   = (const float*)d_in[8];
    float* out = (float*)d_out;

    // workspace layout (floats). Total ~5.6 MB.
    float* w     = (float*)d_ws;
    float* W2t   = w;                       // 16384
    float* cva   = w + 16384;               // 512
    float* f_all = w + 16896;               // 1,048,576
    float* stf   = w + 16896 + 1048576;     // 262,144 (byte off 4,261,888: 16B aligned)
    int*   ids   = (int*)(w + 1327616);     // 65536
    int*   count = (int*)(w + 1393152);     // 1

    k_prep  <<<64,   256, 0, stream>>>(W1, b1, W2, feat, W2t, cva);
    k_march <<<(NR * NS) / 256, 256, 0, stream>>>(ray0, dirs, W1, cva, W2t, b2, W3, b3,
                                                  f_all, count);
    k_cross <<<NR / 256, 256, 0, stream>>>(ray0, dirs, f_all, count, ids,
                                           (float4*)stf, out);
    k_refine<<<NR / 256, 256, 0, stream>>>(ray0, dirs, W1, cva, W2t, b2, W3, b3,
                                           count, ids, (const float4*)stf, out);
}

// Round 2
// 762.735 us; speedup vs baseline: 1.5677x; 1.5677x over previous
//
#include <hip/hip_runtime.h>

static constexpr int   NPB  = 16384;        // rays per batch
static constexpr int   NR   = 4 * NPB;      // 65536 rays total
static constexpr int   NS   = 16;           // march steps
static constexpr int   H    = 128;          // hidden dim
static constexpr float FARV = 2.4f;
static constexpr float EPSF = 1.1920928955078125e-07f; // np.float32 eps

// ---------------------------------------------------------------------------
// Register-friendly MLP eval: k-outer / j-inner with the j-range split into
// two halves (layer 1 recomputed per half: +512 FMA on ~17k, 3%). Live state
// is 64 accumulators instead of h[128] -> no scratch spill (the R1 kernel
// spilled: VGPR=96 < 128 live h floats).
// All weight addresses are wave-uniform -> s_load + v_fmac v,s,v.
// W2 is used in ORIGINAL [k][j] layout (contiguous in j) -> no transpose.
// cv = b1 + feature @ W1[3:35]  (precomputed per batch)
// ---------------------------------------------------------------------------
__device__ __forceinline__ float mlp_eval(
    float px, float py, float pz,
    const float* __restrict__ W1,   // rows 0..2 used: W1[k], W1[H+k], W1[2H+k]
    const float* __restrict__ cv,   // [H]
    const float* __restrict__ W2,   // [H][H] original layout
    const float* __restrict__ b2,   // [H]
    const float* __restrict__ W3,   // [H]
    float b3v)
{
    float f = b3v;
#pragma unroll 1                       // two passes; keep code size small
    for (int p = 0; p < 2; ++p) {
        const float* __restrict__ b2p = b2 + p * 64;
        const float* __restrict__ W3p = W3 + p * 64;
        float a[64];
#pragma unroll
        for (int j = 0; j < 64; ++j) a[j] = b2p[j];
#pragma unroll 2                       // rolled: dep distance 64 hides latency
        for (int k = 0; k < H; ++k) {
            float hk = cv[k];
            hk = fmaf(px, W1[k],         hk);
            hk = fmaf(py, W1[H + k],     hk);
            hk = fmaf(pz, W1[2 * H + k], hk);
            hk = fmaxf(hk, 0.0f);
            const float* __restrict__ w = W2 + k * H + p * 64;
#pragma unroll
            for (int j = 0; j < 64; ++j) a[j] = fmaf(hk, w[j], a[j]);
        }
#pragma unroll
        for (int j = 0; j < 64; ++j)
            f = fmaf(fmaxf(a[j], 0.0f), W3p[j], f);
    }
    return f;
}

// ---------------------------------------------------------------------------
// Prep: per-batch conditioning vectors cv[b] = b1 + feat_b @ W1[3:35].
// ---------------------------------------------------------------------------
__global__ void k_prep(const float* __restrict__ W1, const float* __restrict__ b1,
                       const float* __restrict__ feat, float* __restrict__ cva)
{
    int t = blockIdx.x * blockDim.x + threadIdx.x;   // 512 threads
    if (t >= 4 * H) return;
    int b = t >> 7, kk = t & (H - 1);
    float acc = b1[kk];
#pragma unroll
    for (int i = 0; i < 32; ++i)
        acc = fmaf(feat[b * 32 + i], W1[(3 + i) * H + kk], acc);
    cva[b * H + kk] = acc;
}

// ---------------------------------------------------------------------------
// Phase A: one thread per (ray, step). tid = s*NR + r so f_all writes and the
// later per-step reads are coalesced.
// ---------------------------------------------------------------------------
__global__ __launch_bounds__(256, 4) void k_march(
    const float* __restrict__ ray0, const float* __restrict__ dirs,
    const float* __restrict__ W1,   const float* __restrict__ cva,
    const float* __restrict__ W2,   const float* __restrict__ b2,
    const float* __restrict__ W3,   const float* __restrict__ b3p,
    float* __restrict__ f_all, int* __restrict__ count)
{
    int tid = blockIdx.x * blockDim.x + threadIdx.x; // 1,048,576 threads
    if (tid == 0) *count = 0;                        // zero compaction counter
    int r = tid & (NR - 1);
    int s = tid >> 16;
    float d = ((float)s * (1.0f / 15.0f)) * FARV;
    float ox = ray0[3 * r], oy = ray0[3 * r + 1], oz = ray0[3 * r + 2];
    float dx = dirs[3 * r], dy = dirs[3 * r + 1], dz = dirs[3 * r + 2];
    const float* cv = cva + (r >> 14) * H;
    float f = mlp_eval(fmaf(d, dx, ox), fmaf(d, dy, oy), fmaf(d, dz, oz),
                       W1, cv, W2, b2, W3, *b3p);
    f_all[tid] = f;
}

// ---------------------------------------------------------------------------
// Crossing scan per ray. Unmasked rays finish here (d=FAR); masked rays are
// compacted for the refine kernel.
// ---------------------------------------------------------------------------
__global__ void k_cross(
    const float* __restrict__ ray0, const float* __restrict__ dirs,
    const float* __restrict__ f_all,
    int* __restrict__ count, int* __restrict__ ids,
    float4* __restrict__ state, float* __restrict__ out)
{
    int r = blockIdx.x * blockDim.x + threadIdx.x;   // 65536 threads
    float fv[NS];
#pragma unroll
    for (int s = 0; s < NS; ++s) fv[s] = f_all[s * NR + r];
    int idx = -1; float flo = 0.0f, fhi = 0.0f;
#pragma unroll
    for (int s = NS - 2; s >= 0; --s) {              // reverse => first crossing wins
        if (fv[s] < 0.0f && fv[s + 1] >= 0.0f) { idx = s; flo = fv[s]; fhi = fv[s + 1]; }
    }
    if (idx < 0) {
        float ox = ray0[3 * r], oy = ray0[3 * r + 1], oz = ray0[3 * r + 2];
        float dx = dirs[3 * r], dy = dirs[3 * r + 1], dz = dirs[3 * r + 2];
        out[r] = FARV;
        out[NR + 3 * r + 0] = fmaf(FARV, dx, ox);
        out[NR + 3 * r + 1] = fmaf(FARV, dy, oy);
        out[NR + 3 * r + 2] = fmaf(FARV, dz, oz);
        out[4 * NR + r] = 0.0f;
    } else {
        int slot = atomicAdd(count, 1);
        ids[slot] = r;
        float dlo = ((float)idx * (1.0f / 15.0f)) * FARV;
        float dhi = ((float)(idx + 1) * (1.0f / 15.0f)) * FARV;
        state[slot] = make_float4(dlo, flo, dhi, fhi);
    }
}

// ---------------------------------------------------------------------------
// Phase B: 8 secant iterations for compacted (masked) rays only.
// Hardened vs rocprof-replay artifacts: count clamped, r masked in-bounds.
// ---------------------------------------------------------------------------
__global__ __launch_bounds__(256, 4) void k_refine(
    const float* __restrict__ ray0, const float* __restrict__ dirs,
    const float* __restrict__ W1,   const float* __restrict__ cva,
    const float* __restrict__ W2,   const float* __restrict__ b2,
    const float* __restrict__ W3,   const float* __restrict__ b3p,
    const int* __restrict__ count, const int* __restrict__ ids,
    const float4* __restrict__ state, float* __restrict__ out)
{
    unsigned t = blockIdx.x * blockDim.x + threadIdx.x;   // 65536 threads
    unsigned cnt = (unsigned)*count;
    if (cnt > (unsigned)NR) cnt = (unsigned)NR;           // poison guard
    if (t >= cnt) return;
    int r = ids[t] & (NR - 1);                            // poison guard
    float4 st = state[t];
    float dlo = st.x, flo = st.y, dhi = st.z, fhi = st.w;
    float ox = ray0[3 * r], oy = ray0[3 * r + 1], oz = ray0[3 * r + 2];
    float dx = dirs[3 * r], dy = dirs[3 * r + 1], dz = dirs[3 * r + 2];
    const float* cv = cva + (r >> 14) * H;
    float b3v = *b3p;
#pragma unroll 1   // do NOT unroll: 8x inlined MLP would blow the I$
    for (int it = 0; it < 8; ++it) {
        float dc  = fhi - flo;
        float den = copysignf(fmaxf(fabsf(dc), EPSF), dc);
        float dn  = dlo - (flo * (dhi - dlo)) / den;
        float fn  = mlp_eval(fmaf(dn, dx, ox), fmaf(dn, dy, oy), fmaf(dn, dz, oz),
                             W1, cv, W2, b2, W3, b3v);
        if (fn < 0.0f) { dlo = dn; flo = fn; }
        else           { dhi = dn; fhi = fn; }
    }
    float dc  = fhi - flo;
    float den = copysignf(fmaxf(fabsf(dc), EPSF), dc);
    float dp  = dlo - (flo * (dhi - dlo)) / den;
    out[r] = dp;
    out[NR + 3 * r + 0] = fmaf(dp, dx, ox);
    out[NR + 3 * r + 1] = fmaf(dp, dy, oy);
    out[NR + 3 * r + 2] = fmaf(dp, dz, oz);
    out[4 * NR + r] = 1.0f;
}

// ---------------------------------------------------------------------------
extern "C" void kernel_launch(void* const* d_in, const int* in_sizes, int n_in,
                              void* d_out, int out_size, void* d_ws, size_t ws_size,
                              hipStream_t stream)
{
    const float* ray0 = (const float*)d_in[0];
    const float* dirs = (const float*)d_in[1];
    const float* feat = (const float*)d_in[2];
    const float* W1   = (const float*)d_in[3];
    const float* b1   = (const float*)d_in[4];
    const float* W2   = (const float*)d_in[5];
    const float* b2   = (const float*)d_in[6];
    const float* W3   = (const float*)d_in[7];
    const float* b3   = (const float*)d_in[8];
    float* out = (float*)d_out;

    // workspace layout (floats). Total ~5.6 MB.
    float* w     = (float*)d_ws;
    float* cva   = w;                       // 512
    float* f_all = w + 512;                 // 1,048,576
    float* stf   = w + 512 + 1048576;       // 262,144 (16B-aligned offset)
    int*   ids   = (int*)(w + 1311232);     // 65536
    int*   count = (int*)(w + 1376768);     // 1

    k_prep  <<<2,    256, 0, stream>>>(W1, b1, feat, cva);
    k_march <<<(NR * NS) / 256, 256, 0, stream>>>(ray0, dirs, W1, cva, W2, b2, W3, b3,
                                                  f_all, count);
    k_cross <<<NR / 256, 256, 0, stream>>>(ray0, dirs, f_all, count, ids,
                                           (float4*)stf, out);
    k_refine<<<NR / 256, 256, 0, stream>>>(ray0, dirs, W1, cva, W2, b2, W3, b3,
                                           count, ids, (const float4*)stf, out);
}

// Round 3
// 463.643 us; speedup vs baseline: 2.5789x; 1.6451x over previous
//
#include <hip/hip_runtime.h>

static constexpr int   NPB  = 16384;        // rays per batch
static constexpr int   NR   = 4 * NPB;      // 65536 rays total
static constexpr int   NS   = 16;           // march steps
static constexpr int   H    = 128;          // hidden dim
static constexpr float FARV = 2.4f;
static constexpr float EPSF = 1.1920928955078125e-07f; // np.float32 eps

// ---------------------------------------------------------------------------
// Thread-per-point MLP eval (march): k-outer / j-inner, j split in two halves
// so live state = 64 accumulators (no spill). Weights via wave-uniform s_load.
// ---------------------------------------------------------------------------
__device__ __forceinline__ float mlp_eval(
    float px, float py, float pz,
    const float* __restrict__ W1, const float* __restrict__ cv,
    const float* __restrict__ W2, const float* __restrict__ b2,
    const float* __restrict__ W3, float b3v)
{
    float f = b3v;
#pragma unroll 1
    for (int p = 0; p < 2; ++p) {
        const float* __restrict__ b2p = b2 + p * 64;
        const float* __restrict__ W3p = W3 + p * 64;
        float a[64];
#pragma unroll
        for (int j = 0; j < 64; ++j) a[j] = b2p[j];
#pragma unroll 2
        for (int k = 0; k < H; ++k) {
            float hk = cv[k];
            hk = fmaf(px, W1[k],         hk);
            hk = fmaf(py, W1[H + k],     hk);
            hk = fmaf(pz, W1[2 * H + k], hk);
            hk = fmaxf(hk, 0.0f);
            const float* __restrict__ w = W2 + k * H + p * 64;
#pragma unroll
            for (int j = 0; j < 64; ++j) a[j] = fmaf(hk, w[j], a[j]);
        }
#pragma unroll
        for (int j = 0; j < 64; ++j)
            f = fmaf(fmaxf(a[j], 0.0f), W3p[j], f);
    }
    return f;
}

// ---------------------------------------------------------------------------
// Prep 1: per-batch conditioning vectors cv[b] = b1 + feat_b @ W1[3:35].
// ---------------------------------------------------------------------------
__global__ void k_prep(const float* __restrict__ W1, const float* __restrict__ b1,
                       const float* __restrict__ feat, float* __restrict__ cva)
{
    int t = blockIdx.x * blockDim.x + threadIdx.x;   // 512 threads
    if (t >= 4 * H) return;
    int b = t >> 7, kk = t & (H - 1);
    float acc = b1[kk];
#pragma unroll
    for (int i = 0; i < 32; ++i)
        acc = fmaf(feat[b * 32 + i], W1[(3 + i) * H + kk], acc);
    cva[b * H + kk] = acc;
}

// ---------------------------------------------------------------------------
// Prep 2: pack W2 for the wave-per-ray refine kernel.
// w2q[k2*64 + l] = (W2[2k2][l], W2[2k2][64+l], W2[2k2+1][l], W2[2k2+1][64+l])
// ---------------------------------------------------------------------------
__global__ void k_pairq(const float* __restrict__ W2, float4* __restrict__ w2q)
{
    int t = blockIdx.x * blockDim.x + threadIdx.x;   // 8192 threads
    int k2 = t >> 6, l = t & 63;
    const float* r0 = W2 + (2 * k2) * H;
    const float* r1 = W2 + (2 * k2 + 1) * H;
    w2q[t] = make_float4(r0[l], r0[64 + l], r1[l], r1[64 + l]);
}

// ---------------------------------------------------------------------------
// Phase A: one thread per (ray, step).
// ---------------------------------------------------------------------------
__global__ __launch_bounds__(256, 4) void k_march(
    const float* __restrict__ ray0, const float* __restrict__ dirs,
    const float* __restrict__ W1,   const float* __restrict__ cva,
    const float* __restrict__ W2,   const float* __restrict__ b2,
    const float* __restrict__ W3,   const float* __restrict__ b3p,
    float* __restrict__ f_all, int* __restrict__ count)
{
    int tid = blockIdx.x * blockDim.x + threadIdx.x; // 1,048,576 threads
    if (tid == 0) *count = 0;
    int r = tid & (NR - 1);
    int s = tid >> 16;
    float d = ((float)s * (1.0f / 15.0f)) * FARV;
    float ox = ray0[3 * r], oy = ray0[3 * r + 1], oz = ray0[3 * r + 2];
    float dx = dirs[3 * r], dy = dirs[3 * r + 1], dz = dirs[3 * r + 2];
    const float* cv = cva + (r >> 14) * H;
    float f = mlp_eval(fmaf(d, dx, ox), fmaf(d, dy, oy), fmaf(d, dz, oz),
                       W1, cv, W2, b2, W3, *b3p);
    f_all[tid] = f;
}

// ---------------------------------------------------------------------------
// Crossing scan; unmasked rays finish here, masked rays compacted.
// ---------------------------------------------------------------------------
__global__ void k_cross(
    const float* __restrict__ ray0, const float* __restrict__ dirs,
    const float* __restrict__ f_all,
    int* __restrict__ count, int* __restrict__ ids,
    float4* __restrict__ state, float* __restrict__ out)
{
    int r = blockIdx.x * blockDim.x + threadIdx.x;   // 65536 threads
    float fv[NS];
#pragma unroll
    for (int s = 0; s < NS; ++s) fv[s] = f_all[s * NR + r];
    int idx = -1; float flo = 0.0f, fhi = 0.0f;
#pragma unroll
    for (int s = NS - 2; s >= 0; --s) {
        if (fv[s] < 0.0f && fv[s + 1] >= 0.0f) { idx = s; flo = fv[s]; fhi = fv[s + 1]; }
    }
    if (idx < 0) {
        float ox = ray0[3 * r], oy = ray0[3 * r + 1], oz = ray0[3 * r + 2];
        float dx = dirs[3 * r], dy = dirs[3 * r + 1], dz = dirs[3 * r + 2];
        out[r] = FARV;
        out[NR + 3 * r + 0] = fmaf(FARV, dx, ox);
        out[NR + 3 * r + 1] = fmaf(FARV, dy, oy);
        out[NR + 3 * r + 2] = fmaf(FARV, dz, oz);
        out[4 * NR + r] = 0.0f;
    } else {
        int slot = atomicAdd(count, 1);
        ids[slot] = r;
        float dlo = ((float)idx * (1.0f / 15.0f)) * FARV;
        float dhi = ((float)(idx + 1) * (1.0f / 15.0f)) * FARV;
        state[slot] = make_float4(dlo, flo, dhi, fhi);
    }
}

// ---------------------------------------------------------------------------
// Phase B: WAVE-per-ray secant refine. Lane l owns hidden units {l, 64+l}.
// W2 staged in LDS (64 KB, packed float4 per 2 k-steps); h broadcast via
// v_readlane (compile-time lane index -> SGPR operand of v_fmac).
// ---------------------------------------------------------------------------
__device__ __forceinline__ float lane_bcast(float v, int srcLane) {
    return __int_as_float(__builtin_amdgcn_readlane(__float_as_int(v), srcLane));
}

__global__ __launch_bounds__(256, 2) void k_refine(
    const float* __restrict__ ray0, const float* __restrict__ dirs,
    const float* __restrict__ W1,   const float* __restrict__ cva,
    const float* __restrict__ b2,   const float* __restrict__ W3,
    const float* __restrict__ b3p,  const float4* __restrict__ w2q,
    const int* __restrict__ count,  const int* __restrict__ ids,
    const float4* __restrict__ state, float* __restrict__ out)
{
    __shared__ float4 W2s[4096];                     // exactly 64 KB
    unsigned cnt = (unsigned)*count;
    if (cnt > (unsigned)NR) cnt = (unsigned)NR;      // poison guard
    unsigned base = blockIdx.x << 2;                 // 4 rays (waves) per block
    if (base >= cnt) return;
    for (int i = threadIdx.x; i < 4096; i += 256) W2s[i] = w2q[i];
    __syncthreads();
    unsigned wid = threadIdx.x >> 6, lane = threadIdx.x & 63;
    unsigned t = base + wid;
    if (t >= cnt) return;
    int r = ids[t] & (NR - 1);                       // poison guard
    float4 st = state[t];
    float dlo = st.x, flo = st.y, dhi = st.z, fhi = st.w;
    float ox = ray0[3 * r], oy = ray0[3 * r + 1], oz = ray0[3 * r + 2];
    float dx = dirs[3 * r], dy = dirs[3 * r + 1], dz = dirs[3 * r + 2];
    const float* cv = cva + (r >> 14) * H;
    // per-lane constants for hidden units k0=lane, k1=64+lane
    float w1x0 = W1[lane],      w1y0 = W1[H + lane],      w1z0 = W1[2 * H + lane];
    float w1x1 = W1[64 + lane], w1y1 = W1[H + 64 + lane], w1z1 = W1[2 * H + 64 + lane];
    float cv0 = cv[lane], cv1 = cv[64 + lane];
    float b2a = b2[lane], b2b = b2[64 + lane];
    float w3a = W3[lane], w3b = W3[64 + lane];
    float b3v = *b3p;
    float dp = 0.0f;
#pragma unroll 1
    for (int it = 0; it < 9; ++it) {
        float dc  = fhi - flo;
        float den = copysignf(fmaxf(fabsf(dc), EPSF), dc);
        float dn  = dlo - (flo * (dhi - dlo)) / den;
        if (it == 8) { dp = dn; break; }
        float px = fmaf(dn, dx, ox), py = fmaf(dn, dy, oy), pz = fmaf(dn, dz, oz);
        float h0 = fmaxf(fmaf(px, w1x0, fmaf(py, w1y0, fmaf(pz, w1z0, cv0))), 0.0f);
        float h1 = fmaxf(fmaf(px, w1x1, fmaf(py, w1y1, fmaf(pz, w1z1, cv1))), 0.0f);
        float a0 = b2a, a1 = b2b;
#pragma unroll
        for (int k2 = 0; k2 < 64; ++k2) {
            float4 w = W2s[(k2 << 6) + lane];
            float he = (k2 < 32) ? lane_bcast(h0, 2 * k2)
                                 : lane_bcast(h1, 2 * k2 - 64);
            float ho = (k2 < 32) ? lane_bcast(h0, 2 * k2 + 1)
                                 : lane_bcast(h1, 2 * k2 + 1 - 64);
            a0 = fmaf(he, w.x, a0);
            a1 = fmaf(he, w.y, a1);
            a0 = fmaf(ho, w.z, a0);
            a1 = fmaf(ho, w.w, a1);
        }
        float pf = fmaf(fmaxf(a0, 0.0f), w3a, fmaxf(a1, 0.0f) * w3b);
#pragma unroll
        for (int m = 32; m >= 1; m >>= 1) pf += __shfl_xor(pf, m, 64);
        float fn = pf + b3v;                         // uniform across lanes
        if (fn < 0.0f) { dlo = dn; flo = fn; }
        else           { dhi = dn; fhi = fn; }
    }
    if (lane == 0) {
        out[r] = dp;
        out[NR + 3 * r + 0] = fmaf(dp, dx, ox);
        out[NR + 3 * r + 1] = fmaf(dp, dy, oy);
        out[NR + 3 * r + 2] = fmaf(dp, dz, oz);
        out[4 * NR + r] = 1.0f;
    }
}

// ---------------------------------------------------------------------------
extern "C" void kernel_launch(void* const* d_in, const int* in_sizes, int n_in,
                              void* d_out, int out_size, void* d_ws, size_t ws_size,
                              hipStream_t stream)
{
    const float* ray0 = (const float*)d_in[0];
    const float* dirs = (const float*)d_in[1];
    const float* feat = (const float*)d_in[2];
    const float* W1   = (const float*)d_in[3];
    const float* b1   = (const float*)d_in[4];
    const float* W2   = (const float*)d_in[5];
    const float* b2   = (const float*)d_in[6];
    const float* W3   = (const float*)d_in[7];
    const float* b3   = (const float*)d_in[8];
    float* out = (float*)d_out;

    // workspace layout (floats), ~5.64 MB
    float*  w     = (float*)d_ws;
    float4* w2q   = (float4*)w;                       // 8192 float4 = 32768 f
    float*  cva   = w + 32768;                        // 512
    float*  f_all = w + 33280;                        // 1,048,576
    float*  stf   = w + 1081856;                      // 262,144 (16B aligned)
    int*    ids   = (int*)(w + 1344000);              // 65,536
    int*    count = (int*)(w + 1409536);              // 1

    k_prep  <<<2,    256, 0, stream>>>(W1, b1, feat, cva);
    k_pairq <<<32,   256, 0, stream>>>(W2, w2q);
    k_march <<<(NR * NS) / 256, 256, 0, stream>>>(ray0, dirs, W1, cva, W2, b2, W3, b3,
                                                  f_all, count);
    k_cross <<<NR / 256, 256, 0, stream>>>(ray0, dirs, f_all, count, ids,
                                           (float4*)stf, out);
    k_refine<<<NR / 4, 256, 0, stream>>>(ray0, dirs, W1, cva, b2, W3, b3,
                                         (const float4*)w2q, count, ids,
                                         (const float4*)stf, out);
}